// Round 1
// baseline (216.069 us; speedup 1.0000x reference)
//
#include <hip/hip_runtime.h>
#include <stdint.h>

typedef unsigned short u16;
typedef unsigned int u32;
typedef __attribute__((ext_vector_type(8))) short short8;
typedef __attribute__((ext_vector_type(4))) float floatx4;

__device__ __forceinline__ u16 f2b(float f) {
    u32 u = __builtin_bit_cast(u32, f);
    return (u16)((u + 0x7fffu + ((u >> 16) & 1u)) >> 16);
}

__device__ __forceinline__ void gld16(const void* g, void* l) {
    __builtin_amdgcn_global_load_lds(
        (const __attribute__((address_space(1))) u32*)g,
        (__attribute__((address_space(3))) u32*)l, 16, 0, 0);
}

// ---- Kernel 1: row 2-norm reciprocal + bf16 row-major normalized matrix ----
__global__ __launch_bounds__(256) void rownorm_kernel(
    const float* __restrict__ x, float* __restrict__ rnorm, u16* __restrict__ normRM) {
    int row = blockIdx.x;
    int t = threadIdx.x;
    const float4* xr = (const float4*)(x + (long)row * 1024);
    float4 v = xr[t];
    float ss = v.x * v.x + v.y * v.y + v.z * v.z + v.w * v.w;
    #pragma unroll
    for (int off = 32; off > 0; off >>= 1) ss += __shfl_down(ss, off);
    __shared__ float red[4];
    if ((t & 63) == 0) red[t >> 6] = ss;
    __syncthreads();
    float tot = red[0] + red[1] + red[2] + red[3];
    float r = 1.0f / fmaxf(sqrtf(tot), 1e-12f);
    if (t == 0) rnorm[row] = r;
    ushort4 o;
    o.x = f2b(v.x * r); o.y = f2b(v.y * r); o.z = f2b(v.z * r); o.w = f2b(v.w * r);
    *(ushort4*)(normRM + (long)row * 1024 + t * 4) = o;
}

// ---- Transpose + cast: dA[c][r]=bf16(src[r][c]); dB[c][r]=bf16(src[r][c]*rn[r]) ----
__global__ __launch_bounds__(256) void transpose_cast(
    const float* __restrict__ src, const float* __restrict__ rn,
    u16* __restrict__ dA, u16* __restrict__ dB, int rows, int cols) {
    __shared__ float tile[64][65];
    __shared__ float rbuf[64];
    int r0 = blockIdx.x * 64, c0 = blockIdx.y * 64;
    int t = threadIdx.x;
    #pragma unroll
    for (int i = 0; i < 4; i++) {
        int lin = i * 256 + t;
        int rr = lin >> 4, c4 = (lin & 15) << 2;
        float4 v = *(const float4*)(src + (long)(r0 + rr) * cols + c0 + c4);
        tile[rr][c4] = v.x; tile[rr][c4 + 1] = v.y; tile[rr][c4 + 2] = v.z; tile[rr][c4 + 3] = v.w;
    }
    if (dB != nullptr && t < 64) rbuf[t] = rn[r0 + t];
    __syncthreads();
    #pragma unroll
    for (int i = 0; i < 4; i++) {
        int lin = i * 256 + t;
        int cc = lin >> 4, r4 = (lin & 15) << 2;
        float a0 = tile[r4][cc], a1 = tile[r4 + 1][cc], a2 = tile[r4 + 2][cc], a3 = tile[r4 + 3][cc];
        ushort4 o;
        o.x = f2b(a0); o.y = f2b(a1); o.z = f2b(a2); o.w = f2b(a3);
        *(ushort4*)(dA + (long)(c0 + cc) * rows + r0 + r4) = o;
        if (dB != nullptr) {
            ushort4 p;
            p.x = f2b(a0 * rbuf[r4]); p.y = f2b(a1 * rbuf[r4 + 1]);
            p.z = f2b(a2 * rbuf[r4 + 2]); p.w = f2b(a3 * rbuf[r4 + 3]);
            *(ushort4*)(dB + (long)(c0 + cc) * rows + r0 + r4) = p;
        }
    }
}

// ---- Cast fp32 G -> bf16 ----
__global__ __launch_bounds__(256) void cast_g(const float* __restrict__ G, u16* __restrict__ Gb) {
    long i = ((long)blockIdx.x * 256 + threadIdx.x) * 4;
    float4 v = *(const float4*)(G + i);
    ushort4 o;
    o.x = f2b(v.x); o.y = f2b(v.y); o.z = f2b(v.z); o.w = f2b(v.w);
    *(ushort4*)(Gb + i) = o;
}

// ---- GEMM: C[m][n] = sum_k A[m][k]*B[n][k], A:[M][K] rm, B:[N][K] rm, both bf16 ----
// 128x128 tile, BK=32, 256 threads (4 waves, each 64x64 = 4x4 frags of 16x16x32).
// grid.x = tilesM*tilesN, grid.y = splitK slabs (kIters iters each, kChunk=kIters*32).
__global__ __launch_bounds__(256) void gemm_nt(
    const u16* __restrict__ A, const u16* __restrict__ B,
    float* __restrict__ Cf, u16* __restrict__ Cb,
    int lda, int ldb, int ldc, int tilesN, int kIters, int useAtomic) {
    __shared__ u16 As[128 * 32];
    __shared__ u16 Bs[128 * 32];
    int tile = blockIdx.x;
    int tm = tile / tilesN, tn = tile % tilesN;
    long kOff = (long)blockIdx.y * kIters * 32;
    const u16* Ap = A + (long)tm * 128 * lda + kOff;
    const u16* Bp = B + (long)tn * 128 * ldb + kOff;

    int t = threadIdx.x;
    int lane = t & 63, w = t >> 6;
    int sm = lane >> 2, sk = (lane & 3) * 8;   // staging: 16 rows x 32k per wave-issue
    int wm = (w & 1) * 64, wn = (w >> 1) * 64; // wave sub-tile origin
    int r16 = lane & 15, q = lane >> 4;

    floatx4 acc[4][4];
    #pragma unroll
    for (int i = 0; i < 4; i++)
        #pragma unroll
        for (int j = 0; j < 4; j++) acc[i][j] = (floatx4){0.f, 0.f, 0.f, 0.f};

    for (int kt = 0; kt < kIters; kt++) {
        long kk = (long)kt * 32;
        #pragma unroll
        for (int c = 0; c < 2; c++) {
            int chunk = w * 2 + c;
            int row = chunk * 16 + sm;
            gld16(Ap + (long)row * lda + kk + sk, (void*)&As[((long)chunk * 64 + lane) * 8]);
            gld16(Bp + (long)row * ldb + kk + sk, (void*)&Bs[((long)chunk * 64 + lane) * 8]);
        }
        __syncthreads();
        short8 a[4], b[4];
        #pragma unroll
        for (int i = 0; i < 4; i++) a[i] = *(const short8*)&As[(wm + i * 16 + r16) * 32 + q * 8];
        #pragma unroll
        for (int j = 0; j < 4; j++) b[j] = *(const short8*)&Bs[(wn + j * 16 + r16) * 32 + q * 8];
        #pragma unroll
        for (int i = 0; i < 4; i++)
            #pragma unroll
            for (int j = 0; j < 4; j++)
                acc[i][j] = __builtin_amdgcn_mfma_f32_16x16x32_bf16(a[i], b[j], acc[i][j], 0, 0, 0);
        __syncthreads();
    }

    int m0 = tm * 128 + wm, n0 = tn * 128 + wn;
    #pragma unroll
    for (int i = 0; i < 4; i++) {
        #pragma unroll
        for (int j = 0; j < 4; j++) {
            int mm = m0 + i * 16 + q * 4;
            int nn = n0 + j * 16 + r16;
            #pragma unroll
            for (int r = 0; r < 4; r++) {
                float v = acc[i][j][r];
                long idx = (long)(mm + r) * ldc + nn;
                if (Cb != nullptr) {
                    Cb[idx] = f2b(v);
                } else if (useAtomic) {
                    atomicAdd(&Cf[idx], v);
                } else {
                    Cf[idx] = v;
                }
            }
        }
    }
}

extern "C" void kernel_launch(void* const* d_in, const int* in_sizes, int n_in,
                              void* d_out, int out_size, void* d_ws, size_t ws_size,
                              hipStream_t stream) {
    const float* x = (const float*)d_in[0];
    const float* wgt = (const float*)d_in[1];
    float* out = (float*)d_out;
    char* ws = (char*)d_ws;

    const size_t MB = 1048576;
    float* rnorm  = (float*)ws;                              // 32 KB
    u16*   normRM = (u16*)(ws + 65536);                      // 16 MB  [8192][1024]
    u16*   normT  = (u16*)(ws + 65536 + 16 * MB);            // 16 MB  [1024][8192]
    u16*   xT     = (u16*)(ws + 65536 + 32 * MB);            // 16 MB  [1024][8192]
    u16*   Wt     = (u16*)(ws + 65536 + 48 * MB);            //  2 MB  [1024][1024] = W^T
    u16*   Gb     = (u16*)(ws + 65536 + 50 * MB);            //  2 MB  G bf16
    u16*   Mt     = (u16*)(ws + 65536 + 52 * MB);            //  2 MB  (G·W)^T bf16
    float* G      = (float*)(ws + 65536 + 54 * MB);          //  4 MB  fp32 accum

    // zero G for atomic split-K accumulation (memset nodes are graph-capture safe)
    hipMemsetAsync(G, 0, 1024 * 1024 * sizeof(float), stream);

    // 1) row norms + bf16 row-major normalized x
    rownorm_kernel<<<8192, 256, 0, stream>>>(x, rnorm, normRM);
    // 2) transposed bf16 copies: xT, normT (K-major for the A^T·B GEMM)
    transpose_cast<<<dim3(128, 16), 256, 0, stream>>>(x, rnorm, xT, normT, 8192, 1024);
    //    W^T bf16
    transpose_cast<<<dim3(16, 16), 256, 0, stream>>>(wgt, nullptr, Wt, nullptr, 1024, 1024);
    // 3) G = norm^T · x  (M=N=1024, K=8192, split-K=8, fp32 atomic accumulate)
    gemm_nt<<<dim3(64, 8), 256, 0, stream>>>(normT, xT, G, nullptr, 8192, 8192, 1024, 8, 32, 1);
    // 4) G -> bf16
    cast_g<<<1024, 256, 0, stream>>>(G, Gb);
    // 5) Mt = (G·W)^T = W^T · G   (M=N=1024, K=1024) -> bf16
    gemm_nt<<<dim3(64, 1), 256, 0, stream>>>(Wt, Gb, nullptr, Mt, 1024, 1024, 1024, 8, 32, 0);
    // 6) out = norm · M  (M=8192, N=1024, K=1024) -> fp32
    gemm_nt<<<dim3(512, 1), 256, 0, stream>>>(normRM, Mt, out, nullptr, 1024, 1024, 1024, 8, 32, 0);
}

// Round 2
// 208.570 us; speedup vs baseline: 1.0360x; 1.0360x over previous
//
#include <hip/hip_runtime.h>
#include <stdint.h>

typedef unsigned short u16;
typedef unsigned int u32;
typedef __attribute__((ext_vector_type(8))) short short8;
typedef __attribute__((ext_vector_type(4))) float floatx4;

__device__ __forceinline__ u16 f2b(float f) {
    u32 u = __builtin_bit_cast(u32, f);
    return (u16)((u + 0x7fffu + ((u >> 16) & 1u)) >> 16);
}

__device__ __forceinline__ void gld16(const void* g, void* l) {
    __builtin_amdgcn_global_load_lds(
        (const __attribute__((address_space(1))) u32*)g,
        (__attribute__((address_space(3))) u32*)l, 16, 0, 0);
}

// ---- prep: row 2-norm recips (r and sqrt(r)) + bf16 row-major x ----
__global__ __launch_bounds__(256) void prep_kernel(
    const float* __restrict__ x, float* __restrict__ rnorm,
    float* __restrict__ srnorm, u16* __restrict__ xb) {
    int row = blockIdx.x;
    int t = threadIdx.x;
    const float4* xr = (const float4*)(x + (long)row * 1024);
    float4 v = xr[t];
    float ss = v.x * v.x + v.y * v.y + v.z * v.z + v.w * v.w;
    #pragma unroll
    for (int off = 32; off > 0; off >>= 1) ss += __shfl_down(ss, off);
    __shared__ float red[4];
    if ((t & 63) == 0) red[t >> 6] = ss;
    __syncthreads();
    float tot = red[0] + red[1] + red[2] + red[3];
    float r = 1.0f / fmaxf(sqrtf(tot), 1e-12f);
    if (t == 0) { rnorm[row] = r; srnorm[row] = sqrtf(r); }
    ushort4 o;
    o.x = f2b(v.x); o.y = f2b(v.y); o.z = f2b(v.z); o.w = f2b(v.w);
    *(ushort4*)(xb + (long)row * 1024 + t * 4) = o;
}

// ---- transpose+scale+cast: dst[c][r] = bf16(src[r][c] * (sr ? sr[r] : 1)) ----
__global__ __launch_bounds__(256) void transpose_scale(
    const float* __restrict__ src, const float* __restrict__ sr,
    u16* __restrict__ dst, int rows, int cols) {
    __shared__ float tile[64][65];
    __shared__ float rbuf[64];
    int r0 = blockIdx.x * 64, c0 = blockIdx.y * 64;
    int t = threadIdx.x;
    #pragma unroll
    for (int i = 0; i < 4; i++) {
        int lin = i * 256 + t;
        int rr = lin >> 4, c4 = (lin & 15) << 2;
        float4 v = *(const float4*)(src + (long)(r0 + rr) * cols + c0 + c4);
        tile[rr][c4] = v.x; tile[rr][c4 + 1] = v.y; tile[rr][c4 + 2] = v.z; tile[rr][c4 + 3] = v.w;
    }
    if (t < 64) rbuf[t] = (sr != nullptr) ? sr[r0 + t] : 1.0f;
    __syncthreads();
    #pragma unroll
    for (int i = 0; i < 4; i++) {
        int lin = i * 256 + t;
        int cc = lin >> 4, r4 = (lin & 15) << 2;
        ushort4 o;
        o.x = f2b(tile[r4][cc] * rbuf[r4]);
        o.y = f2b(tile[r4 + 1][cc] * rbuf[r4 + 1]);
        o.z = f2b(tile[r4 + 2][cc] * rbuf[r4 + 2]);
        o.w = f2b(tile[r4 + 3][cc] * rbuf[r4 + 3]);
        *(ushort4*)(dst + (long)(c0 + cc) * rows + r0 + r4) = o;
    }
}

// ---- cast fp32 -> bf16 (count must be multiple of 1024) ----
__global__ __launch_bounds__(256) void cast_f2b(const float* __restrict__ S, u16* __restrict__ D) {
    long i = ((long)blockIdx.x * 256 + threadIdx.x) * 4;
    float4 v = *(const float4*)(S + i);
    ushort4 o;
    o.x = f2b(v.x); o.y = f2b(v.y); o.z = f2b(v.z); o.w = f2b(v.w);
    *(ushort4*)(D + i) = o;
}

// ---- GEMM: C[m][n] = rs[m] * sum_k A[m][k]*B[n][k]; A:[M][K] rm, B:[N][K] rm, bf16 ----
// 128x128 tile, BK=32, 512 threads (8 waves, each 64x32 = 4x2 frags of 16x16x32).
// grid.x = tilesM*tilesN (opt. XCD-swizzled), grid.y = splitK slabs of kIters.
__global__ __launch_bounds__(512) void gemm_nt(
    const u16* __restrict__ A, const u16* __restrict__ B,
    float* __restrict__ Cf, u16* __restrict__ Cb, const float* __restrict__ rowscale,
    int lda, int ldb, int ldc, int tilesN, int kIters, int useAtomic, int swizzle) {
    __shared__ u16 As[128 * 32];
    __shared__ u16 Bs[128 * 32];
    int bid = blockIdx.x;
    int tm, tn;
    if (swizzle) {  // 64x8 tiles: same-XCD blocks (bid%8 equal) share an 8-tile band of A
        tm = (bid & 7) * 8 + ((bid >> 3) & 7);
        tn = bid >> 6;
    } else {
        tm = bid / tilesN; tn = bid % tilesN;
    }
    long kOff = (long)blockIdx.y * kIters * 32;
    const u16* Ap = A + (long)tm * 128 * lda + kOff;
    const u16* Bp = B + (long)tn * 128 * ldb + kOff;

    int t = threadIdx.x;
    int lane = t & 63, w = t >> 6;
    int sm = lane >> 2, sk = (lane & 3) * 8;   // staging: thread t covers row w*16+sm, k-bytes sk*2
    int wm = (w & 1) * 64, wn = (w >> 1) * 32; // wave sub-tile origin (64m x 32n)
    int r16 = lane & 15, q = lane >> 4;
    int srow = w * 16 + sm;

    floatx4 acc[4][2];
    #pragma unroll
    for (int i = 0; i < 4; i++)
        #pragma unroll
        for (int j = 0; j < 2; j++) acc[i][j] = (floatx4){0.f, 0.f, 0.f, 0.f};

    for (int kt = 0; kt < kIters; kt++) {
        long kk = (long)kt * 32;
        gld16(Ap + (long)srow * lda + kk + sk, (void*)&As[(long)t * 8]);
        gld16(Bp + (long)srow * ldb + kk + sk, (void*)&Bs[(long)t * 8]);
        __syncthreads();
        short8 a[4], b[2];
        #pragma unroll
        for (int i = 0; i < 4; i++) a[i] = *(const short8*)&As[(wm + i * 16 + r16) * 32 + q * 8];
        #pragma unroll
        for (int j = 0; j < 2; j++) b[j] = *(const short8*)&Bs[(wn + j * 16 + r16) * 32 + q * 8];
        #pragma unroll
        for (int i = 0; i < 4; i++)
            #pragma unroll
            for (int j = 0; j < 2; j++)
                acc[i][j] = __builtin_amdgcn_mfma_f32_16x16x32_bf16(a[i], b[j], acc[i][j], 0, 0, 0);
        __syncthreads();
    }

    int m0 = tm * 128 + wm, n0 = tn * 128 + wn;
    #pragma unroll
    for (int i = 0; i < 4; i++) {
        int mm = m0 + i * 16 + q * 4;
        float rs[4];
        #pragma unroll
        for (int r = 0; r < 4; r++) rs[r] = (rowscale != nullptr) ? rowscale[mm + r] : 1.0f;
        #pragma unroll
        for (int j = 0; j < 2; j++) {
            int nn = n0 + j * 16 + r16;
            #pragma unroll
            for (int r = 0; r < 4; r++) {
                float v = acc[i][j][r] * rs[r];
                long idx = (long)(mm + r) * ldc + nn;
                if (Cb != nullptr) {
                    Cb[idx] = f2b(v);
                } else if (useAtomic) {
                    atomicAdd(&Cf[idx], v);
                } else {
                    Cf[idx] = v;
                }
            }
        }
    }
}

extern "C" void kernel_launch(void* const* d_in, const int* in_sizes, int n_in,
                              void* d_out, int out_size, void* d_ws, size_t ws_size,
                              hipStream_t stream) {
    const float* x = (const float*)d_in[0];
    const float* wgt = (const float*)d_in[1];
    float* out = (float*)d_out;
    char* ws = (char*)d_ws;

    const size_t MB = 1048576;
    float* rnorm  = (float*)ws;                       // 32 KB
    float* srnorm = (float*)(ws + 32768);             // 32 KB
    u16*   xb     = (u16*)(ws + 65536);               // 16 MB  bf16(x) row-major
    u16*   YT     = (u16*)(ws + 65536 + 16 * MB);     // 16 MB  bf16(sqrt(r)x)^T [1024][8192]
    u16*   Wt     = (u16*)(ws + 65536 + 32 * MB);     //  2 MB  W^T bf16
    u16*   Gb     = (u16*)(ws + 65536 + 34 * MB);     //  2 MB  G bf16
    u16*   Mt     = (u16*)(ws + 65536 + 36 * MB);     //  2 MB  M^T bf16
    float* G      = (float*)(ws + 65536 + 38 * MB);   //  4 MB  fp32 split-K accum
    float* Mtf    = (float*)(ws + 65536 + 42 * MB);   //  4 MB  fp32 split-K accum

    // zero both split-K accumulators in one memset (they're contiguous)
    hipMemsetAsync(G, 0, 8 * MB, stream);

    // W^T (independent of x path)
    transpose_scale<<<dim3(16, 16), 256, 0, stream>>>(wgt, nullptr, Wt, 1024, 1024);
    // row norms + xb
    prep_kernel<<<8192, 256, 0, stream>>>(x, rnorm, srnorm, xb);
    // YT = (diag(sqrt r) x)^T  bf16
    transpose_scale<<<dim3(128, 16), 256, 0, stream>>>(x, srnorm, YT, 8192, 1024);
    // G = Y^T Y  (M=N=1024, K=8192, split-K=8, atomic fp32)
    gemm_nt<<<dim3(64, 8), 512, 0, stream>>>(YT, YT, G, nullptr, nullptr,
                                             8192, 8192, 1024, 8, 32, 1, 0);
    cast_f2b<<<1024, 256, 0, stream>>>(G, Gb);
    // Mtf = W^T G = M^T  (M=N=1024, K=1024, split-K=8, atomic fp32)
    gemm_nt<<<dim3(64, 8), 512, 0, stream>>>(Wt, Gb, Mtf, nullptr, nullptr,
                                             1024, 1024, 1024, 8, 4, 1, 0);
    cast_f2b<<<1024, 256, 0, stream>>>(Mtf, Mt);
    // out = diag(rnorm) xb M  (M=8192, N=1024, K=1024), XCD-swizzled
    gemm_nt<<<dim3(512, 1), 512, 0, stream>>>(xb, Mt, out, nullptr, rnorm,
                                              1024, 1024, 1024, 8, 32, 0, 1);
}

// Round 3
// 176.987 us; speedup vs baseline: 1.2208x; 1.1784x over previous
//
#include <hip/hip_runtime.h>
#include <stdint.h>

typedef unsigned short u16;
typedef unsigned int u32;
typedef __attribute__((ext_vector_type(8))) short short8;
typedef __attribute__((ext_vector_type(4))) float floatx4;

__device__ __forceinline__ u16 f2b(float f) {
    u32 u = __builtin_bit_cast(u32, f);
    return (u16)((u + 0x7fffu + ((u >> 16) & 1u)) >> 16);
}

__device__ __forceinline__ void gld16(const void* g, void* l) {
    __builtin_amdgcn_global_load_lds(
        (const __attribute__((address_space(1))) u32*)g,
        (__attribute__((address_space(3))) u32*)l, 16, 0, 0);
}

// ---- row 2-norm recips: rnorm = 1/max(||row||,eps), srnorm = sqrt(rnorm) ----
__global__ __launch_bounds__(256) void prep_norms(
    const float* __restrict__ x, float* __restrict__ rnorm, float* __restrict__ srnorm) {
    int row = blockIdx.x;
    int t = threadIdx.x;
    float4 v = ((const float4*)(x + (long)row * 1024))[t];
    float ss = v.x * v.x + v.y * v.y + v.z * v.z + v.w * v.w;
    #pragma unroll
    for (int off = 32; off > 0; off >>= 1) ss += __shfl_down(ss, off);
    __shared__ float red[4];
    if ((t & 63) == 0) red[t >> 6] = ss;
    __syncthreads();
    if (t == 0) {
        float r = 1.0f / fmaxf(sqrtf(red[0] + red[1] + red[2] + red[3]), 1e-12f);
        rnorm[row] = r;
        srnorm[row] = sqrtf(r);
    }
}

// ---- transpose+scale+cast: dst[c][r] = bf16(src[r][c] * (sr ? sr[r] : 1)) ----
__global__ __launch_bounds__(256) void transpose_scale(
    const float* __restrict__ src, const float* __restrict__ sr,
    u16* __restrict__ dst, int rows, int cols) {
    __shared__ float tile[64][65];
    __shared__ float rbuf[64];
    int r0 = blockIdx.x * 64, c0 = blockIdx.y * 64;
    int t = threadIdx.x;
    #pragma unroll
    for (int i = 0; i < 4; i++) {
        int lin = i * 256 + t;
        int rr = lin >> 4, c4 = (lin & 15) << 2;
        float4 v = *(const float4*)(src + (long)(r0 + rr) * cols + c0 + c4);
        tile[rr][c4] = v.x; tile[rr][c4 + 1] = v.y; tile[rr][c4 + 2] = v.z; tile[rr][c4 + 3] = v.w;
    }
    if (t < 64) rbuf[t] = (sr != nullptr) ? sr[r0 + t] : 1.0f;
    __syncthreads();
    #pragma unroll
    for (int i = 0; i < 4; i++) {
        int lin = i * 256 + t;
        int cc = lin >> 4, r4 = (lin & 15) << 2;
        ushort4 o;
        o.x = f2b(tile[r4][cc] * rbuf[r4]);
        o.y = f2b(tile[r4 + 1][cc] * rbuf[r4 + 1]);
        o.z = f2b(tile[r4 + 2][cc] * rbuf[r4 + 2]);
        o.w = f2b(tile[r4 + 3][cc] * rbuf[r4 + 3]);
        *(ushort4*)(dst + (long)(c0 + cc) * rows + r0 + r4) = o;
    }
}

// ---- elementwise fp32 -> bf16 (count multiple of 1024) ----
__global__ __launch_bounds__(256) void cast_f2b(const float* __restrict__ S, u16* __restrict__ D) {
    long i = ((long)blockIdx.x * 256 + threadIdx.x) * 4;
    float4 v = *(const float4*)(S + i);
    ushort4 o;
    o.x = f2b(v.x); o.y = f2b(v.y); o.z = f2b(v.z); o.w = f2b(v.w);
    *(ushort4*)(D + i) = o;
}

// ---- reduce S split-K slabs of E fp32 each -> bf16 ----
__global__ __launch_bounds__(256) void reduce_cast(
    const float* __restrict__ P, u16* __restrict__ D, int S, long E) {
    long i = ((long)blockIdx.x * 256 + threadIdx.x) * 4;
    float4 s = *(const float4*)(P + i);
    for (int z = 1; z < S; z++) {
        float4 v = *(const float4*)(P + z * E + i);
        s.x += v.x; s.y += v.y; s.z += v.z; s.w += v.w;
    }
    ushort4 o;
    o.x = f2b(s.x); o.y = f2b(s.y); o.z = f2b(s.z); o.w = f2b(s.w);
    *(ushort4*)(D + i) = o;
}

// ---- GEMM: C[m][n] (+= per z-slab) = rs[m] * sum_k A[m][k]*B[n][k] ----
// A:[M][K] rm bf16, B:[N][K] rm bf16. Tile 64(M) x 128(N), BK=64, 256 threads
// (4 waves as 2x2 of 32x64 wave-tiles). XOR-swizzled LDS: chunk (row,c) of 8
// halves stored at chunk-slot c^(row&7) -> conflict-free b128 frag reads.
// grid.x = tilesM*tilesN, grid.y = split-K slab (kIters BK-steps each), plain
// fp32 stores to C + z*coffz.
__global__ __launch_bounds__(256, 4) void gemm64x128(
    const u16* __restrict__ A, const u16* __restrict__ B,
    float* __restrict__ C, const float* __restrict__ rowscale,
    int lda, int ldb, int ldc, int tilesN, int kIters, long coffz) {
    __shared__ __align__(16) u16 As[64 * 64];    //  8 KB
    __shared__ __align__(16) u16 Bs[128 * 64];   // 16 KB
    int bid = blockIdx.x;
    int tm = bid / tilesN, tn = bid % tilesN;
    long kOff = (long)blockIdx.y * kIters * 64;
    const u16* Ap = A + (long)tm * 64 * lda + kOff;
    const u16* Bp = B + (long)tn * 128 * ldb + kOff;
    long coff = (long)blockIdx.y * coffz;

    int t = threadIdx.x;
    int lane = t & 63, w = t >> 6;
    int wm = (w & 1) * 32, wn = (w >> 1) * 64;
    int r16 = lane & 15, q = lane >> 4;

    // staging chunk-linear ids (LDS dest = uniform base + lane*16)
    int acl[2], bcl[4];
    #pragma unroll
    for (int j = 0; j < 2; j++) acl[j] = (w * 2 + j) * 64 + lane;
    #pragma unroll
    for (int j = 0; j < 4; j++) bcl[j] = (w * 4 + j) * 64 + lane;

    floatx4 acc[2][4];
    #pragma unroll
    for (int i = 0; i < 2; i++)
        #pragma unroll
        for (int j = 0; j < 4; j++) acc[i][j] = (floatx4){0.f, 0.f, 0.f, 0.f};

    for (int kt = 0; kt < kIters; kt++) {
        long kk = (long)kt * 64;
        #pragma unroll
        for (int j = 0; j < 2; j++) {
            int cl = acl[j], row = cl >> 3, cg = (cl & 7) ^ (row & 7);
            gld16(Ap + (long)row * lda + kk + cg * 8, (void*)&As[cl * 8]);
        }
        #pragma unroll
        for (int j = 0; j < 4; j++) {
            int cl = bcl[j], row = cl >> 3, cg = (cl & 7) ^ (row & 7);
            gld16(Bp + (long)row * ldb + kk + cg * 8, (void*)&Bs[cl * 8]);
        }
        __syncthreads();
        #pragma unroll
        for (int ks = 0; ks < 2; ks++) {
            short8 a[2], b[4];
            #pragma unroll
            for (int i = 0; i < 2; i++) {
                int r = wm + i * 16 + r16;
                int c = (ks * 4 + q) ^ (r & 7);
                a[i] = *(const short8*)&As[r * 64 + c * 8];
            }
            #pragma unroll
            for (int j = 0; j < 4; j++) {
                int r = wn + j * 16 + r16;
                int c = (ks * 4 + q) ^ (r & 7);
                b[j] = *(const short8*)&Bs[r * 64 + c * 8];
            }
            #pragma unroll
            for (int i = 0; i < 2; i++)
                #pragma unroll
                for (int j = 0; j < 4; j++)
                    acc[i][j] = __builtin_amdgcn_mfma_f32_16x16x32_bf16(a[i], b[j], acc[i][j], 0, 0, 0);
        }
        __syncthreads();
    }

    int m0 = tm * 64 + wm, n0 = tn * 128 + wn;
    #pragma unroll
    for (int i = 0; i < 2; i++) {
        int mm = m0 + i * 16 + q * 4;
        float rs[4];
        #pragma unroll
        for (int r = 0; r < 4; r++) rs[r] = (rowscale != nullptr) ? rowscale[mm + r] : 1.0f;
        #pragma unroll
        for (int j = 0; j < 4; j++) {
            int nn = n0 + j * 16 + r16;
            #pragma unroll
            for (int r = 0; r < 4; r++)
                C[coff + (long)(mm + r) * ldc + nn] = acc[i][j][r] * rs[r];
        }
    }
}

extern "C" void kernel_launch(void* const* d_in, const int* in_sizes, int n_in,
                              void* d_out, int out_size, void* d_ws, size_t ws_size,
                              hipStream_t stream) {
    const float* x = (const float*)d_in[0];
    const float* wgt = (const float*)d_in[1];
    float* out = (float*)d_out;
    char* ws = (char*)d_ws;

    const size_t MB = 1048576;
    float* rnorm  = (float*)ws;                       // 32 KB
    float* srnorm = (float*)(ws + 32768);             // 32 KB
    u16*   YT     = (u16*)(ws + 65536);               // 16 MB  bf16(diag(sqrt r)·x)^T [1024][8192]
    u16*   Wt     = (u16*)(ws + 65536 + 16 * MB);     //  2 MB  W^T bf16
    u16*   Gb     = (u16*)(ws + 65536 + 18 * MB);     //  2 MB  G bf16
    u16*   Mt     = (u16*)(ws + 65536 + 20 * MB);     //  2 MB  M^T bf16
    char*  REGION = ws + 65536 + 22 * MB;             // 32 MB time-shared:
    float* Gp     = (float*)REGION;                   //   steps 4-5: 8x4MB G partials
    u16*   xb     = (u16*)REGION;                     //   after: bf16(x) [8192][1024] (16 MB)
    float* Mp     = (float*)(REGION + 16 * MB);       //   after: 2x4MB M^T partials
    // total 54.06 MB

    // 1) row norms
    prep_norms<<<8192, 256, 0, stream>>>(x, rnorm, srnorm);
    // 2) YT = (diag(sqrt r)·x)^T bf16
    transpose_scale<<<dim3(128, 16), 256, 0, stream>>>(x, srnorm, YT, 8192, 1024);
    // 3) Wt = W^T bf16
    transpose_scale<<<dim3(16, 16), 256, 0, stream>>>(wgt, nullptr, Wt, 1024, 1024);
    // 4) G partials: G = Y^T·Y (M=N=1024, K=8192, split-K=8) -> Gp
    gemm64x128<<<dim3(128, 8), 256, 0, stream>>>(YT, YT, Gp, nullptr,
                                                 8192, 8192, 1024, 8, 16, 1048576);
    // 5) Gb = bf16(sum Gp)
    reduce_cast<<<1024, 256, 0, stream>>>(Gp, Gb, 8, 1048576);
    // 6) xb = bf16(x)  (REGION free now)
    cast_f2b<<<8192, 256, 0, stream>>>(x, xb);
    // 7) M^T partials: C = W^T·G (M=N=1024, K=1024, split-K=2) -> Mp
    gemm64x128<<<dim3(128, 2), 256, 0, stream>>>(Wt, Gb, Mp, nullptr,
                                                 1024, 1024, 1024, 8, 8, 1048576);
    // 8) Mt = bf16(sum Mp)
    reduce_cast<<<1024, 256, 0, stream>>>(Mp, Mt, 2, 1048576);
    // 9) out = diag(rnorm)·xb·M  (M=8192, N=1024, K=1024, 1024 blocks)
    gemm64x128<<<dim3(1024, 1), 256, 0, stream>>>(xb, Mt, out, rnorm,
                                                  1024, 1024, 1024, 8, 16, 0);
}

// Round 4
// 167.579 us; speedup vs baseline: 1.2894x; 1.0561x over previous
//
#include <hip/hip_runtime.h>
#include <stdint.h>

typedef unsigned short u16;
typedef unsigned int u32;
typedef __attribute__((ext_vector_type(8))) short short8;
typedef __attribute__((ext_vector_type(4))) float floatx4;

__device__ __forceinline__ u16 f2b(float f) {
    u32 u = __builtin_bit_cast(u32, f);
    return (u16)((u + 0x7fffu + ((u >> 16) & 1u)) >> 16);
}

__device__ __forceinline__ void gld16(const void* g, void* l) {
    __builtin_amdgcn_global_load_lds(
        (const __attribute__((address_space(1))) u32*)g,
        (__attribute__((address_space(3))) u32*)l, 16, 0, 0);
}

// ---- row 2-norm recips: rnorm = 1/max(||row||,eps), srnorm = sqrt(rnorm) ----
__global__ __launch_bounds__(256) void prep_norms(
    const float* __restrict__ x, float* __restrict__ rnorm, float* __restrict__ srnorm) {
    int row = blockIdx.x;
    int t = threadIdx.x;
    float4 v = ((const float4*)(x + (long)row * 1024))[t];
    float ss = v.x * v.x + v.y * v.y + v.z * v.z + v.w * v.w;
    #pragma unroll
    for (int off = 32; off > 0; off >>= 1) ss += __shfl_down(ss, off);
    __shared__ float red[4];
    if ((t & 63) == 0) red[t >> 6] = ss;
    __syncthreads();
    if (t == 0) {
        float r = 1.0f / fmaxf(sqrtf(red[0] + red[1] + red[2] + red[3]), 1e-12f);
        rnorm[row] = r;
        srnorm[row] = sqrtf(r);
    }
}

// ---- dual-output scale+cast: dstT[c][r] = dstR[r][c] = bf16(src[r][c]*sr[r]) ----
__global__ __launch_bounds__(256) void transpose_scale_dual(
    const float* __restrict__ src, const float* __restrict__ sr,
    u16* __restrict__ dstT, u16* __restrict__ dstR, int rows, int cols) {
    __shared__ float tile[64][65];
    __shared__ float rbuf[64];
    int r0 = blockIdx.x * 64, c0 = blockIdx.y * 64;
    int t = threadIdx.x;
    if (t < 64) rbuf[t] = (sr != nullptr) ? sr[r0 + t] : 1.0f;
    __syncthreads();
    #pragma unroll
    for (int i = 0; i < 4; i++) {
        int lin = i * 256 + t;
        int rr = lin >> 4, c4 = (lin & 15) << 2;
        float4 v = *(const float4*)(src + (long)(r0 + rr) * cols + c0 + c4);
        float s = rbuf[rr];
        v.x *= s; v.y *= s; v.z *= s; v.w *= s;
        tile[rr][c4] = v.x; tile[rr][c4 + 1] = v.y; tile[rr][c4 + 2] = v.z; tile[rr][c4 + 3] = v.w;
        if (dstR != nullptr) {
            ushort4 o; o.x = f2b(v.x); o.y = f2b(v.y); o.z = f2b(v.z); o.w = f2b(v.w);
            *(ushort4*)(dstR + (long)(r0 + rr) * cols + c0 + c4) = o;
        }
    }
    __syncthreads();
    #pragma unroll
    for (int i = 0; i < 4; i++) {
        int lin = i * 256 + t;
        int cc = lin >> 4, r4 = (lin & 15) << 2;
        ushort4 o;
        o.x = f2b(tile[r4][cc]);
        o.y = f2b(tile[r4 + 1][cc]);
        o.z = f2b(tile[r4 + 2][cc]);
        o.w = f2b(tile[r4 + 3][cc]);
        *(ushort4*)(dstT + (long)(c0 + cc) * rows + r0 + r4) = o;
    }
}

// ---- reduce S split-K slabs of E fp32 each -> bf16 (plain, full coverage) ----
__global__ __launch_bounds__(256) void reduce_cast(
    const float* __restrict__ P, u16* __restrict__ D, int S, long E) {
    long i = ((long)blockIdx.x * 256 + threadIdx.x) * 4;
    float4 s = *(const float4*)(P + i);
    for (int z = 1; z < S; z++) {
        float4 v = *(const float4*)(P + z * E + i);
        s.x += v.x; s.y += v.y; s.z += v.z; s.w += v.w;
    }
    ushort4 o;
    o.x = f2b(s.x); o.y = f2b(s.y); o.z = f2b(s.z); o.w = f2b(s.w);
    *(ushort4*)(D + i) = o;
}

// ---- symmetric reduce for G (1024x1024, ldc=1024): GEMM computed only tiles
// (tm,tn128) with tm<=2*tn128+1. 64x64 output tiles: kept -> direct sum;
// dropped -> sum mirrored (kept) tile coalesced, LDS-transpose, write. ----
__global__ __launch_bounds__(256) void reduce_sym64(
    const float* __restrict__ P, u16* __restrict__ D, int S, long E) {
    __shared__ float lt[64][65];
    int ti = blockIdx.x >> 4, tj = blockIdx.x & 15;
    int t = threadIdx.x;
    int r = t >> 4, c4 = (t & 15) << 2;
    int kept = (ti <= 2 * (tj >> 1) + 1);
    if (kept) {
        #pragma unroll
        for (int it = 0; it < 4; it++) {
            int row = 64 * ti + it * 16 + r;
            long idx = (long)row * 1024 + 64 * tj + c4;
            float4 s = *(const float4*)(P + idx);
            for (int z = 1; z < S; z++) {
                float4 v = *(const float4*)(P + (long)z * E + idx);
                s.x += v.x; s.y += v.y; s.z += v.z; s.w += v.w;
            }
            ushort4 o; o.x = f2b(s.x); o.y = f2b(s.y); o.z = f2b(s.z); o.w = f2b(s.w);
            *(ushort4*)(D + idx) = o;
        }
    } else {
        #pragma unroll
        for (int it = 0; it < 4; it++) {
            int row = it * 16 + r;  // row within mirrored source tile
            long idx = (long)(64 * tj + row) * 1024 + 64 * ti + c4;
            float4 s = *(const float4*)(P + idx);
            for (int z = 1; z < S; z++) {
                float4 v = *(const float4*)(P + (long)z * E + idx);
                s.x += v.x; s.y += v.y; s.z += v.z; s.w += v.w;
            }
            lt[row][c4] = s.x; lt[row][c4 + 1] = s.y; lt[row][c4 + 2] = s.z; lt[row][c4 + 3] = s.w;
        }
        __syncthreads();
        #pragma unroll
        for (int it = 0; it < 4; it++) {
            int dr = it * 16 + r;
            ushort4 o;
            o.x = f2b(lt[c4 + 0][dr]); o.y = f2b(lt[c4 + 1][dr]);
            o.z = f2b(lt[c4 + 2][dr]); o.w = f2b(lt[c4 + 3][dr]);
            *(ushort4*)(D + (long)(64 * ti + dr) * 1024 + 64 * tj + c4) = o;
        }
    }
}

// ---- GEMM: C[m][n] (per z-slab) = rs[m] * sum_k A[m][k]*B[n][k] ----
// A:[M][K] rm bf16, B:[N][K] rm bf16. Tile 64(M) x 128(N), BK=64, 256 threads
// (4 waves as 2x2 of 32x64 wave-tiles). XOR-swizzled LDS, conflict-free b128.
// sym=1: grid.x=72 upper-triangular tiles (tm<=2*tn+1) of a 16x8 tile grid.
__global__ __launch_bounds__(256, 4) void gemm64x128(
    const u16* __restrict__ A, const u16* __restrict__ B,
    float* __restrict__ C, const float* __restrict__ rowscale,
    int lda, int ldb, int ldc, int tilesN, int kIters, long coffz, int sym) {
    __shared__ __align__(16) u16 As[64 * 64];    //  8 KB
    __shared__ __align__(16) u16 Bs[128 * 64];   // 16 KB
    int tm, tn;
    if (sym) {
        int id = blockIdx.x, j = 0;
        while (true) {
            int c = (2 * j + 2 < 16) ? (2 * j + 2) : 16;
            if (id < c) break;
            id -= c; j++;
        }
        tn = j; tm = id;
    } else {
        tm = blockIdx.x / tilesN; tn = blockIdx.x % tilesN;
    }
    long kOff = (long)blockIdx.y * kIters * 64;
    const u16* Ap = A + (long)tm * 64 * lda + kOff;
    const u16* Bp = B + (long)tn * 128 * ldb + kOff;
    long coff = (long)blockIdx.y * coffz;

    int t = threadIdx.x;
    int lane = t & 63, w = t >> 6;
    int wm = (w & 1) * 32, wn = (w >> 1) * 64;
    int r16 = lane & 15, q = lane >> 4;

    int acl[2], bcl[4];
    #pragma unroll
    for (int j = 0; j < 2; j++) acl[j] = (w * 2 + j) * 64 + lane;
    #pragma unroll
    for (int j = 0; j < 4; j++) bcl[j] = (w * 4 + j) * 64 + lane;

    floatx4 acc[2][4];
    #pragma unroll
    for (int i = 0; i < 2; i++)
        #pragma unroll
        for (int j = 0; j < 4; j++) acc[i][j] = (floatx4){0.f, 0.f, 0.f, 0.f};

    for (int kt = 0; kt < kIters; kt++) {
        long kk = (long)kt * 64;
        #pragma unroll
        for (int j = 0; j < 2; j++) {
            int cl = acl[j], row = cl >> 3, cg = (cl & 7) ^ (row & 7);
            gld16(Ap + (long)row * lda + kk + cg * 8, (void*)&As[cl * 8]);
        }
        #pragma unroll
        for (int j = 0; j < 4; j++) {
            int cl = bcl[j], row = cl >> 3, cg = (cl & 7) ^ (row & 7);
            gld16(Bp + (long)row * ldb + kk + cg * 8, (void*)&Bs[cl * 8]);
        }
        __syncthreads();
        #pragma unroll
        for (int ks = 0; ks < 2; ks++) {
            short8 a[2], b[4];
            #pragma unroll
            for (int i = 0; i < 2; i++) {
                int rr = wm + i * 16 + r16;
                int cc = (ks * 4 + q) ^ (rr & 7);
                a[i] = *(const short8*)&As[rr * 64 + cc * 8];
            }
            #pragma unroll
            for (int j = 0; j < 4; j++) {
                int rr = wn + j * 16 + r16;
                int cc = (ks * 4 + q) ^ (rr & 7);
                b[j] = *(const short8*)&Bs[rr * 64 + cc * 8];
            }
            #pragma unroll
            for (int i = 0; i < 2; i++)
                #pragma unroll
                for (int j = 0; j < 4; j++)
                    acc[i][j] = __builtin_amdgcn_mfma_f32_16x16x32_bf16(a[i], b[j], acc[i][j], 0, 0, 0);
        }
        __syncthreads();
    }

    int m0 = tm * 64 + wm, n0 = tn * 128 + wn;
    #pragma unroll
    for (int i = 0; i < 2; i++) {
        int mm = m0 + i * 16 + q * 4;
        float rs[4];
        #pragma unroll
        for (int r = 0; r < 4; r++) rs[r] = (rowscale != nullptr) ? rowscale[mm + r] : 1.0f;
        #pragma unroll
        for (int j = 0; j < 4; j++) {
            int nn = n0 + j * 16 + r16;
            #pragma unroll
            for (int r = 0; r < 4; r++)
                C[coff + (long)(mm + r) * ldc + nn] = acc[i][j][r] * rs[r];
        }
    }
}

extern "C" void kernel_launch(void* const* d_in, const int* in_sizes, int n_in,
                              void* d_out, int out_size, void* d_ws, size_t ws_size,
                              hipStream_t stream) {
    const float* x = (const float*)d_in[0];
    const float* wgt = (const float*)d_in[1];
    float* out = (float*)d_out;
    char* ws = (char*)d_ws;

    const size_t MB = 1048576;
    float* rnorm  = (float*)ws;                       // 32 KB
    float* srnorm = (float*)(ws + 32768);             // 32 KB
    u16*   YT     = (u16*)(ws + 65536);               // 16 MB  Y^T = (diag(sqrt r)x)^T [1024][8192]
    u16*   Yb     = (u16*)(ws + 65536 + 16 * MB);     // 16 MB  Y row-major [8192][1024]
    u16*   Wt     = (u16*)(ws + 65536 + 32 * MB);     //  2 MB  W^T bf16
    u16*   Gb     = (u16*)(ws + 65536 + 34 * MB);     //  2 MB  G bf16
    u16*   Mt     = (u16*)(ws + 65536 + 36 * MB);     //  2 MB  M^T bf16
    float* Gp     = (float*)(ws + 65536 + 38 * MB);   // 32 MB  8x4MB G partials
    float* Mp     = (float*)(ws + 65536 + 70 * MB);   //  8 MB  2x4MB M^T partials
    // total ~78 MB

    // 1) row norms
    prep_norms<<<8192, 256, 0, stream>>>(x, rnorm, srnorm);
    // 2) Y in both layouts from one read of x
    transpose_scale_dual<<<dim3(128, 16), 256, 0, stream>>>(x, srnorm, YT, Yb, 8192, 1024);
    // 3) Wt = W^T bf16
    transpose_scale_dual<<<dim3(16, 16), 256, 0, stream>>>(wgt, nullptr, Wt, nullptr, 1024, 1024);
    // 4) G = Y^T·Y, upper-tri tiles only (72 of 128), split-K=8 -> Gp
    gemm64x128<<<dim3(72, 8), 256, 0, stream>>>(YT, YT, Gp, nullptr,
                                                8192, 8192, 1024, 8, 16, 1048576, 1);
    // 5) Gb = bf16(sum Gp), mirroring the lower triangle
    reduce_sym64<<<256, 256, 0, stream>>>(Gp, Gb, 8, 1048576);
    // 6) M^T = W^T·G (G symmetric), split-K=2 -> Mp
    gemm64x128<<<dim3(128, 2), 256, 0, stream>>>(Wt, Gb, Mp, nullptr,
                                                 1024, 1024, 1024, 8, 8, 1048576, 0);
    // 7) Mt = bf16(sum Mp)
    reduce_cast<<<1024, 256, 0, stream>>>(Mp, Mt, 2, 1048576);
    // 8) out = diag(sqrt r)·Y·M  (M=8192, N=1024, K=1024, 1024 blocks)
    gemm64x128<<<dim3(1024, 1), 256, 0, stream>>>(Yb, Mt, out, srnorm,
                                                  1024, 1024, 1024, 8, 16, 0, 0);
}